// Round 7
// baseline (220.939 us; speedup 1.0000x reference)
//
#include <hip/hip_runtime.h>
#include <stdint.h>

// loss = sum_{b,m,n} | dot(src[b,n,:], tgts[b,m,n,:]) |
// B=64, M=16, N=64, D=1024
//
// DMA-streaming (T3/T4): one wave per (b, n, m-half), all fetches via
// global_load_lds, hand-counted s_waitcnt vmcnt(8) (never drains to 0 in
// steady state). src staged through ring slot 2 (48 KiB LDS -> 3 blocks/CU).
//
// R7: single-dispatch. Final reduction fused via "last ticket" protocol:
// each block writes its partial, __threadfence(), device-scope ticket
// fetch_add; the block whose ticket == gridDim-1 (mod gridDim) gathers all
// partials with device-scope acquire loads and writes d_out. Exactly one
// such block per replay for ANY initial counter value, so the 0xAA-poisoned
// counter in d_ws is harmless and never needs re-zeroing. No spin-waits.

typedef __attribute__((ext_vector_type(4))) float f32x4;
typedef const __attribute__((address_space(1))) void* gvp;
typedef __attribute__((address_space(3))) void* svp;

#define GLDS(gp, lp) \
  __builtin_amdgcn_global_load_lds((gvp)(gp), (svp)(lp), 16, 0, 0)

#define WAITV(n) asm volatile("s_waitcnt vmcnt(" #n ")" ::: "memory")
#define CFENCE() asm volatile("" ::: "memory")

#define NBLOCKS 2048

__global__ __launch_bounds__(256) void orth_loss_main(
    const float* __restrict__ src,
    const float* __restrict__ tgts,
    float* __restrict__ partials,     // d_ws[0..NBLOCKS)
    unsigned int* __restrict__ counter, // d_ws + NBLOCKS floats
    float* __restrict__ out)
{
    __shared__ float ring[4][3][1024];   // 4 waves x 3 row-buffers x 4 KiB
    __shared__ float sbuf[4];
    __shared__ int   is_last;

    const int wave = threadIdx.x >> 6;   // 0..3
    const int lane = threadIdx.x & 63;

    const int w  = blockIdx.x * 4 + wave;   // 0..8191, exact grid
    const int n  = w & 63;                  // N = 64
    const int t  = w >> 6;
    const int mh = t & 1;                   // m-half: rows m = mh*8 + 0..7
    const int b  = t >> 1;

    const float* srow = src + ((size_t)(b * 64 + n)) * 1024 + lane * 4;
    const int    base_row = (b * 16 + mh * 8) * 64 + n;
    const float* trow = tgts + (size_t)base_row * 1024 + lane * 4;
    const size_t mstride = (size_t)64 * 1024;   // floats between m-rows

    // ---- prologue: src -> ring[2], row0 -> ring[0], row1 -> ring[1] ----
#pragma unroll
    for (int k = 0; k < 4; ++k)
        GLDS(srow + k * 256, &ring[wave][2][k * 256]);
#pragma unroll
    for (int r = 0; r < 2; ++r) {
#pragma unroll
        for (int k = 0; k < 4; ++k)
            GLDS(trow + r * mstride + k * 256, &ring[wave][r][k * 256]);
    }

    // pre-step: wait for src (oldest 4 of 12), pull to regs, issue row2
    WAITV(8);
    f32x4 s0, s1, s2, s3;
    {
        const f32x4* sb_ = (const f32x4*)&ring[wave][2][0];
        s0 = sb_[lane];       s1 = sb_[lane + 64];
        s2 = sb_[lane + 128]; s3 = sb_[lane + 192];
    }
    CFENCE();   // ds_reads of src stay above the overwrite of ring[2]
    asm volatile("s_waitcnt lgkmcnt(0)" ::: "memory");  // src regs live
    CFENCE();
#pragma unroll
    for (int k = 0; k < 4; ++k)
        GLDS(trow + 2 * mstride + k * 256, &ring[wave][2][k * 256]);

    float local = 0.0f;

    // steps 0..7: wait vmcnt(8) (oldest row done, 2 rows in flight),
    // compute from ring[i%3], reuse that slot for row i+3. Tail: 8 -> 4 -> 0.
#define STEP(MI, DO_ISSUE, WN) do {                                          \
      WAITV(WN);                                                             \
      const f32x4* lb_ = (const f32x4*)&ring[wave][(MI) % 3][0];             \
      const f32x4 t0 = lb_[lane];                                            \
      const f32x4 t1 = lb_[lane + 64];                                       \
      const f32x4 t2 = lb_[lane + 128];                                      \
      const f32x4 t3 = lb_[lane + 192];                                      \
      float dot = 0.0f;                                                      \
      dot = fmaf(t0.x, s0.x, dot); dot = fmaf(t0.y, s0.y, dot);              \
      dot = fmaf(t0.z, s0.z, dot); dot = fmaf(t0.w, s0.w, dot);              \
      dot = fmaf(t1.x, s1.x, dot); dot = fmaf(t1.y, s1.y, dot);              \
      dot = fmaf(t1.z, s1.z, dot); dot = fmaf(t1.w, s1.w, dot);              \
      dot = fmaf(t2.x, s2.x, dot); dot = fmaf(t2.y, s2.y, dot);              \
      dot = fmaf(t2.z, s2.z, dot); dot = fmaf(t2.w, s2.w, dot);              \
      dot = fmaf(t3.x, s3.x, dot); dot = fmaf(t3.y, s3.y, dot);              \
      dot = fmaf(t3.z, s3.z, dot); dot = fmaf(t3.w, s3.w, dot);              \
      _Pragma("unroll")                                                      \
      for (int off = 32; off > 0; off >>= 1)                                 \
          dot += __shfl_down(dot, off, 64);                                  \
      if (lane == 0) local += fabsf(dot);                                    \
      CFENCE(); /* LDS reads above, next GLDS below */                       \
      if (DO_ISSUE) {                                                        \
        _Pragma("unroll")                                                    \
        for (int k = 0; k < 4; ++k)                                          \
            GLDS(trow + ((MI) + 3) * mstride + k * 256,                      \
                 &ring[wave][(MI) % 3][k * 256]);                            \
      }                                                                      \
    } while (0)

    STEP(0, 1, 8);
    STEP(1, 1, 8);
    STEP(2, 1, 8);
    STEP(3, 1, 8);
    STEP(4, 1, 8);
    STEP(5, 0, 8);
    STEP(6, 0, 4);
    STEP(7, 0, 0);
#undef STEP

    if (lane == 0) sbuf[wave] = local;
    __syncthreads();

    // ---- fused finalization: last-ticket block reduces all partials ----
    if (threadIdx.x == 0) {
        const float p = sbuf[0] + sbuf[1] + sbuf[2] + sbuf[3];
        partials[blockIdx.x] = p;
        __threadfence();   // publish partial before taking ticket
        const unsigned int ticket = __hip_atomic_fetch_add(
            counter, 1u, __ATOMIC_ACQ_REL, __HIP_MEMORY_SCOPE_AGENT);
        // exactly one block per replay satisfies this, for ANY counter init
        is_last = ((ticket & (NBLOCKS - 1)) == (NBLOCKS - 1)) ? 1 : 0;
    }
    __syncthreads();

    if (is_last) {
        float s = 0.0f;
        for (int i = threadIdx.x; i < NBLOCKS; i += 256)
            s += __hip_atomic_load(&partials[i], __ATOMIC_ACQUIRE,
                                   __HIP_MEMORY_SCOPE_AGENT);
#pragma unroll
        for (int off = 32; off > 0; off >>= 1)
            s += __shfl_down(s, off, 64);
        if (lane == 0) sbuf[wave] = s;
        __syncthreads();
        if (threadIdx.x == 0)
            out[0] = sbuf[0] + sbuf[1] + sbuf[2] + sbuf[3];
    }
}

extern "C" void kernel_launch(void* const* d_in, const int* in_sizes, int n_in,
                              void* d_out, int out_size, void* d_ws, size_t ws_size,
                              hipStream_t stream) {
    const float* src  = (const float*)d_in[0];   // [B, N, D]
    const float* tgts = (const float*)d_in[1];   // [B, M, N, D]
    float* out      = (float*)d_out;             // [1]
    float* partials = (float*)d_ws;              // NBLOCKS floats
    unsigned int* counter = (unsigned int*)((float*)d_ws + NBLOCKS);

    // one wave per (b, n, m-half): B*N*2 waves = 8192, 4 waves/block
    orth_loss_main<<<NBLOCKS, 256, 0, stream>>>(src, tgts, partials, counter, out);
}

// Round 8
// 56.557 us; speedup vs baseline: 3.9065x; 3.9065x over previous
//
#include <hip/hip_runtime.h>
#include <stdint.h>

// loss = sum_{b,m,n} | dot(src[b,n,:], tgts[b,m,n,:]) |
// B=64, M=16, N=64, D=1024
//
// R8 = R5 main kernel (best measured: 50.28 us) with the trailing reduce
// dispatch replaced by v1's finalization: upfront 4-byte memset + one plain
// device-scope atomicAdd per block (no fences -- R7 showed agent-scope
// fences per block cost 4.4x via per-XCD L2 writebacks).
//
// Main kernel: DMA-streaming (T3/T4). One wave per (b, n, m-half); all
// fetches via global_load_lds into a per-wave 3-deep LDS ring; hand-counted
// s_waitcnt vmcnt(8) never drains to 0 in steady state (2 rows = 8 KiB
// always in flight per wave).

typedef __attribute__((ext_vector_type(4))) float f32x4;
typedef const __attribute__((address_space(1))) void* gvp;
typedef __attribute__((address_space(3))) void* svp;

#define GLDS(gp, lp) \
  __builtin_amdgcn_global_load_lds((gvp)(gp), (svp)(lp), 16, 0, 0)

#define WAITV(n) asm volatile("s_waitcnt vmcnt(" #n ")" ::: "memory")
#define CFENCE() asm volatile("" ::: "memory")

__global__ __launch_bounds__(256) void orth_loss_main(
    const float* __restrict__ src,
    const float* __restrict__ tgts,
    float* __restrict__ out)
{
    __shared__ float ring[4][3][1024];   // 4 waves x 3 row-buffers x 4 KiB
    __shared__ float srcb[4][1024];      // 4 waves x src row
    __shared__ float sbuf[4];

    const int wave = threadIdx.x >> 6;   // 0..3
    const int lane = threadIdx.x & 63;

    const int w  = blockIdx.x * 4 + wave;   // 0..8191, exact grid
    const int n  = w & 63;                  // N = 64
    const int t  = w >> 6;
    const int mh = t & 1;                   // m-half: rows m = mh*8 + 0..7
    const int b  = t >> 1;

    const float* srow = src + ((size_t)(b * 64 + n)) * 1024 + lane * 4;
    const int    base_row = (b * 16 + mh * 8) * 64 + n;
    const float* trow = tgts + (size_t)base_row * 1024 + lane * 4;
    const size_t mstride = (size_t)64 * 1024;   // floats between m-rows

    // ---- prologue: src (4 ops) + rows 0,1,2 (12 ops) = 16 outstanding ----
#pragma unroll
    for (int k = 0; k < 4; ++k)
        GLDS(srow + k * 256, &srcb[wave][k * 256]);
#pragma unroll
    for (int r = 0; r < 3; ++r) {
#pragma unroll
        for (int k = 0; k < 4; ++k)
            GLDS(trow + r * mstride + k * 256, &ring[wave][r][k * 256]);
    }

    float local = 0.0f;
    f32x4 s0, s1, s2, s3;

    // Steady state: wait vmcnt(8) (oldest row + src done, 2 rows stay in
    // flight), compute from LDS, then reuse the just-consumed buffer for
    // row mi+3. Tail: vmcnt 8 -> 4 -> 0.
#define STEP(MI, DO_ISSUE, WN) do {                                          \
      WAITV(WN);                                                             \
      if ((MI) == 0) {                                                       \
        const f32x4* sb_ = (const f32x4*)&srcb[wave][0];                     \
        s0 = sb_[lane];       s1 = sb_[lane + 64];                           \
        s2 = sb_[lane + 128]; s3 = sb_[lane + 192];                          \
      }                                                                      \
      const f32x4* lb_ = (const f32x4*)&ring[wave][(MI) % 3][0];             \
      const f32x4 t0 = lb_[lane];                                            \
      const f32x4 t1 = lb_[lane + 64];                                       \
      const f32x4 t2 = lb_[lane + 128];                                      \
      const f32x4 t3 = lb_[lane + 192];                                      \
      float dot = 0.0f;                                                      \
      dot = fmaf(t0.x, s0.x, dot); dot = fmaf(t0.y, s0.y, dot);              \
      dot = fmaf(t0.z, s0.z, dot); dot = fmaf(t0.w, s0.w, dot);              \
      dot = fmaf(t1.x, s1.x, dot); dot = fmaf(t1.y, s1.y, dot);              \
      dot = fmaf(t1.z, s1.z, dot); dot = fmaf(t1.w, s1.w, dot);              \
      dot = fmaf(t2.x, s2.x, dot); dot = fmaf(t2.y, s2.y, dot);              \
      dot = fmaf(t2.z, s2.z, dot); dot = fmaf(t2.w, s2.w, dot);              \
      dot = fmaf(t3.x, s3.x, dot); dot = fmaf(t3.y, s3.y, dot);              \
      dot = fmaf(t3.z, s3.z, dot); dot = fmaf(t3.w, s3.w, dot);              \
      _Pragma("unroll")                                                      \
      for (int off = 32; off > 0; off >>= 1)                                 \
          dot += __shfl_down(dot, off, 64);                                  \
      if (lane == 0) local += fabsf(dot);                                    \
      CFENCE(); /* keep ds_reads above, next GLDS below */                   \
      if (DO_ISSUE) {                                                        \
        _Pragma("unroll")                                                    \
        for (int k = 0; k < 4; ++k)                                          \
            GLDS(trow + ((MI) + 3) * mstride + k * 256,                      \
                 &ring[wave][(MI) % 3][k * 256]);                            \
      }                                                                      \
    } while (0)

    STEP(0, 1, 8);
    STEP(1, 1, 8);
    STEP(2, 1, 8);
    STEP(3, 1, 8);
    STEP(4, 1, 8);
    STEP(5, 0, 8);
    STEP(6, 0, 4);
    STEP(7, 0, 0);
#undef STEP

    if (lane == 0) sbuf[wave] = local;
    __syncthreads();

    if (threadIdx.x == 0) {
        const float s = sbuf[0] + sbuf[1] + sbuf[2] + sbuf[3];
        atomicAdd(out, s);   // plain device-scope fp32 atomic, no fences
    }
}

extern "C" void kernel_launch(void* const* d_in, const int* in_sizes, int n_in,
                              void* d_out, int out_size, void* d_ws, size_t ws_size,
                              hipStream_t stream) {
    const float* src  = (const float*)d_in[0];   // [B, N, D]
    const float* tgts = (const float*)d_in[1];   // [B, M, N, D]
    float* out = (float*)d_out;                  // [1]

    // one wave per (b, n, m-half): B*N*2 waves = 8192, 4 waves/block
    const int total_waves = (in_sizes[0] / 1024) * 2;   // 8192
    const int blocks = total_waves / 4;                  // 2048

    hipMemsetAsync(out, 0, sizeof(float), stream);
    orth_loss_main<<<blocks, 256, 0, stream>>>(src, tgts, out);
}

// Round 9
// 49.601 us; speedup vs baseline: 4.4544x; 1.1402x over previous
//
#include <hip/hip_runtime.h>
#include <stdint.h>

// loss = sum_{b,m,n} | dot(src[b,n,:], tgts[b,m,n,:]) |
// B=64, M=16, N=64, D=1024
//
// R9 = R5 (best: 50.28 us) with two changes:
//  1. one wave per (b, n) covering ALL 16 m-rows (was 2 tasks of 8):
//     src fetched once per (b,n) -> logical bytes 288 -> 272 MiB, and half
//     as many pipeline prologue/tail ramps.
//  2. next-row global_load_lds issued BEFORE the serial shuffle-reduce
//     (after an explicit lgkmcnt(0) so the ds_reads of that ring slot have
//     completed) -- shortens per-step consume-to-reissue by ~200 cycles.
// Finalization = R5's proven separate 1-block reduce dispatch (R8 showed
// memset+atomicAdd costs ~6 us more).
//
// Steady state: hand-counted s_waitcnt vmcnt(8) -- 2 rows (8 KiB/wave)
// always in flight, queue never drains to 0 until the tail.

typedef __attribute__((ext_vector_type(4))) float f32x4;
typedef const __attribute__((address_space(1))) void* gvp;
typedef __attribute__((address_space(3))) void* svp;

#define GLDS(gp, lp) \
  __builtin_amdgcn_global_load_lds((gvp)(gp), (svp)(lp), 16, 0, 0)

#define WAITV(n)  asm volatile("s_waitcnt vmcnt(" #n ")" ::: "memory")
#define WAITLGKM() asm volatile("s_waitcnt lgkmcnt(0)" ::: "memory")
#define CFENCE() asm volatile("" ::: "memory")

__global__ __launch_bounds__(256) void orth_loss_main(
    const float* __restrict__ src,
    const float* __restrict__ tgts,
    float* __restrict__ partials)
{
    __shared__ float ring[4][3][1024];   // 4 waves x 3 row-buffers x 4 KiB
    __shared__ float srcb[4][1024];      // 4 waves x src row
    __shared__ float sbuf[4];

    const int wave = threadIdx.x >> 6;   // 0..3
    const int lane = threadIdx.x & 63;

    const int w = blockIdx.x * 4 + wave;    // 0..4095, exact grid
    const int n = w & 63;                   // N = 64
    const int b = w >> 6;                   // B = 64

    const float* srow = src + ((size_t)(b * 64 + n)) * 1024 + lane * 4;
    const int    base_row = (b * 16) * 64 + n;      // m = 0..15
    const float* trow = tgts + (size_t)base_row * 1024 + lane * 4;
    const size_t mstride = (size_t)64 * 1024;       // floats between m-rows

    // ---- prologue: src (4 ops) + rows 0,1,2 (12 ops) = 16 outstanding ----
#pragma unroll
    for (int k = 0; k < 4; ++k)
        GLDS(srow + k * 256, &srcb[wave][k * 256]);
#pragma unroll
    for (int r = 0; r < 3; ++r) {
#pragma unroll
        for (int k = 0; k < 4; ++k)
            GLDS(trow + r * mstride + k * 256, &ring[wave][r][k * 256]);
    }

    float local = 0.0f;
    f32x4 s0, s1, s2, s3;

    // step MI: wait vmcnt(WN) (row MI + [src at MI=0] done, 2 rows in
    // flight), ds_read row, FMA, issue row MI+3 into the just-read slot,
    // then the serial shuffle reduce. Tail waits: 8 ... 8, 4, 0.
#define STEP(MI, DO_ISSUE, WN) do {                                          \
      WAITV(WN);                                                             \
      if ((MI) == 0) {                                                       \
        const f32x4* sb_ = (const f32x4*)&srcb[wave][0];                     \
        s0 = sb_[lane];       s1 = sb_[lane + 64];                           \
        s2 = sb_[lane + 128]; s3 = sb_[lane + 192];                          \
      }                                                                      \
      const f32x4* lb_ = (const f32x4*)&ring[wave][(MI) % 3][0];             \
      const f32x4 t0 = lb_[lane];                                            \
      const f32x4 t1 = lb_[lane + 64];                                       \
      const f32x4 t2 = lb_[lane + 128];                                      \
      const f32x4 t3 = lb_[lane + 192];                                      \
      float dot = 0.0f;                                                      \
      dot = fmaf(t0.x, s0.x, dot); dot = fmaf(t0.y, s0.y, dot);              \
      dot = fmaf(t0.z, s0.z, dot); dot = fmaf(t0.w, s0.w, dot);              \
      dot = fmaf(t1.x, s1.x, dot); dot = fmaf(t1.y, s1.y, dot);              \
      dot = fmaf(t1.z, s1.z, dot); dot = fmaf(t1.w, s1.w, dot);              \
      dot = fmaf(t2.x, s2.x, dot); dot = fmaf(t2.y, s2.y, dot);              \
      dot = fmaf(t2.z, s2.z, dot); dot = fmaf(t2.w, s2.w, dot);              \
      dot = fmaf(t3.x, s3.x, dot); dot = fmaf(t3.y, s3.y, dot);              \
      dot = fmaf(t3.z, s3.z, dot); dot = fmaf(t3.w, s3.w, dot);              \
      CFENCE();                                                              \
      if (DO_ISSUE) {                                                        \
        WAITLGKM(); /* ring-slot ds_reads complete before overwrite */       \
        CFENCE();                                                            \
        _Pragma("unroll")                                                    \
        for (int k = 0; k < 4; ++k)                                          \
            GLDS(trow + ((MI) + 3) * mstride + k * 256,                      \
                 &ring[wave][(MI) % 3][k * 256]);                            \
        CFENCE();                                                            \
      }                                                                      \
      _Pragma("unroll")                                                      \
      for (int off = 32; off > 0; off >>= 1)                                 \
          dot += __shfl_down(dot, off, 64);                                  \
      if (lane == 0) local += fabsf(dot);                                    \
    } while (0)

    STEP( 0, 1, 8);
    STEP( 1, 1, 8);
    STEP( 2, 1, 8);
    STEP( 3, 1, 8);
    STEP( 4, 1, 8);
    STEP( 5, 1, 8);
    STEP( 6, 1, 8);
    STEP( 7, 1, 8);
    STEP( 8, 1, 8);
    STEP( 9, 1, 8);
    STEP(10, 1, 8);
    STEP(11, 1, 8);
    STEP(12, 1, 8);
    STEP(13, 0, 8);
    STEP(14, 0, 4);
    STEP(15, 0, 0);
#undef STEP

    if (lane == 0) sbuf[wave] = local;
    __syncthreads();
    if (threadIdx.x == 0)
        partials[blockIdx.x] = sbuf[0] + sbuf[1] + sbuf[2] + sbuf[3];
}

__global__ __launch_bounds__(256) void reduce_partials(
    const float* __restrict__ partials, float* __restrict__ out, int n)
{
    __shared__ float sb[4];
    const int lane = threadIdx.x & 63;
    const int wv   = threadIdx.x >> 6;
    float s = 0.0f;
    for (int i = threadIdx.x; i < n; i += 256) s += partials[i];
#pragma unroll
    for (int off = 32; off > 0; off >>= 1) s += __shfl_down(s, off, 64);
    if (lane == 0) sb[wv] = s;
    __syncthreads();
    if (threadIdx.x == 0) out[0] = sb[0] + sb[1] + sb[2] + sb[3];
}

extern "C" void kernel_launch(void* const* d_in, const int* in_sizes, int n_in,
                              void* d_out, int out_size, void* d_ws, size_t ws_size,
                              hipStream_t stream) {
    const float* src  = (const float*)d_in[0];   // [B, N, D]
    const float* tgts = (const float*)d_in[1];   // [B, M, N, D]
    float* out      = (float*)d_out;             // [1]
    float* partials = (float*)d_ws;              // 1024 floats

    // one wave per (b, n): B*N waves = 4096, 4 waves/block
    const int total_waves = in_sizes[0] / 1024;  // 4096
    const int blocks = total_waves / 4;          // 1024

    orth_loss_main<<<blocks, 256, 0, stream>>>(src, tgts, partials);
    reduce_partials<<<1, 256, 0, stream>>>(partials, out, blocks);
}